// Round 5
// baseline (2116.973 us; speedup 1.0000x reference)
//
#include <hip/hip_runtime.h>
#include <stdint.h>

// ---------------------------------------------------------------------------
// SNN categorical policy forward (B=1024, C_IN=8, HID=300, OUT=2, T=300)
//
// R5: LDS-resident lane-private sliding window (spill-proof layer 1).
//  K1: grid (5,1024), 64 threads (1 wave). Lane owns neuron h. The 109-deep
//      x-history lives in LDS ring[slot][lane] (slot = t & 127, +13 mirror
//      slots so any 14-consecutive-slot read is wrap-free with static
//      ds_read offsets). Registers hold only one tap-group's staging
//      (14 f32 + 14 f64) + acc[10] f64 -> ~130 VGPR, no spill.
//      enc packed to 8-bit masks (adding +0.0 vs the reference's 0*w = +/-0.0
//      is bit-identical for the f32 add chain). FIR: f64, j ascending ->
//      same canonical sums as verified R2-R4. sched_barrier every 2 groups
//      caps scheduler hoisting (R3/R4 spill lesson) but allows 2-deep
//      read/FMA pipelining.
//  K2: unchanged from R3/R4 (verified bit-exact).
// ---------------------------------------------------------------------------

#define NB    1024
#define CIN   8
#define HID   300
#define TLEN  300
#define KTAP  99
#define THETA 10.0f
#define TB    10
#define RING_SLOTS 141          // 128 ring + 13 mirror

__device__ __forceinline__ void threefry2x32(uint32_t c0, uint32_t c1,
                                             uint32_t& o0, uint32_t& o1) {
  const uint32_t k0 = 0u, k1 = 42u;
  const uint32_t k2 = k0 ^ k1 ^ 0x1BD11BDAu;
  uint32_t x0 = c0 + k0, x1 = c1 + k1;
#define TFR(r) { x0 += x1; x1 = (x1 << (r)) | (x1 >> (32 - (r))); x1 ^= x0; }
  TFR(13) TFR(15) TFR(26) TFR(6)  x0 += k1; x1 += k2 + 1u;
  TFR(17) TFR(29) TFR(16) TFR(24) x0 += k2; x1 += k0 + 2u;
  TFR(13) TFR(15) TFR(26) TFR(6)  x0 += k0; x1 += k1 + 3u;
  TFR(17) TFR(29) TFR(16) TFR(24) x0 += k1; x1 += k2 + 4u;
  TFR(13) TFR(15) TFR(26) TFR(6)  x0 += k2; x1 += k0 + 5u;
#undef TFR
  o0 = x0; o1 = x1;
}

__device__ __forceinline__ float jax_uniform_from_bits(uint32_t bits) {
  uint32_t fb = (bits >> 9) | 0x3F800000u;
  float f = __uint_as_float(fb) - 1.0f;
  const float tiny = 1.17549435e-38f;
  float u = __fadd_rn(f, tiny);
  return fmaxf(tiny, u);
}

// ======================= Kernel 1: layer-1 SNN ============================
__global__ __launch_bounds__(64, 1)
void snn_l1_kernel(const float* __restrict__ enc,
                   const float* __restrict__ W1,
                   unsigned long long* __restrict__ maskG) {
  __shared__ float    ring[RING_SLOTS * 64];   // 36096 B, lane-private columns
  __shared__ double   kD[100];                 //   800 B
  __shared__ uint32_t encB[TLEN];              //  1200 B

  const int lane = threadIdx.x;
  const int bh   = blockIdx.x;          // h-chunk [0,5)
  const int b    = blockIdx.y;
  const int h    = bh * 64 + lane;

  // taps: identical formula to verified R2-R4 kernels
  for (int j = lane; j < 100; j += 64) {
    float q  = (float)j / 10.0f;
    float ef = (float)exp((double)(1.0f - q));
    kD[j] = (double)__fmul_rn(q, ef);
  }
  // pack enc bits: enc values are exactly 0.0f or 1.0f
  for (int t = lane; t < TLEN; t += 64) {
    uint32_t m = 0u;
#pragma unroll
    for (int c = 0; c < CIN; ++c)
      if (enc[b * (CIN * TLEN) + c * TLEN + t] != 0.0f) m |= (1u << c);
    encB[t] = m;
  }
  // zero the ring (zero history for t<0)
  for (int m = 0; m < RING_SLOTS; ++m)
    ring[m * 64 + lane] = 0.0f;
  __syncthreads();

  float w1f[8];
#pragma unroll
  for (int c = 0; c < 8; ++c)
    w1f[c] = (h < HID) ? W1[h * 8 + c] : 0.0f;

  const float arf = (float)0.6065306597126334;   // f32(exp(-0.5))
  const float Af  = (float)-27.182818284590452;  // f32(-10e)

  float RX = 0.0f, RY = 0.0f;
  unsigned long long* mptr = maskG + b * (TLEN * 5) + bh;

  for (int tb = 0; tb < TLEN / TB; ++tb) {
    const int t0 = tb * TB;
    const int s0 = t0 & 127;

    // ---- phase 1: x[t0..t0+9] (bit-identical f32 chain), write to ring ----
#pragma unroll
    for (int i = 0; i < TB; ++i) {
      const uint32_t bits = encB[t0 + i];
      float xf = 0.0f;
#pragma unroll
      for (int c = 0; c < 8; ++c) {
        float wsel = (bits & (1u << c)) ? w1f[c] : 0.0f;
        xf = __fadd_rn(xf, wsel);
      }
      const int slot = (s0 + i) & 127;
      ring[slot * 64 + lane] = xf;
      if (slot < RING_SLOTS - 128)                 // mirror for wrap-free reads
        ring[(slot + 128) * 64 + lane] = xf;
    }
    __builtin_amdgcn_sched_barrier(0);

    // ---- phase 2: FIR, f64, j ascending (canonical sums as R2-R4) ----
    double acc[TB];
#pragma unroll
    for (int i = 0; i < TB; ++i) acc[i] = 0.0;

#pragma unroll
    for (int g = 0; g < 20; ++g) {
      const int jlo = 5 * g + 1;
      const int jhi = (5 * g + 5 < 99) ? (5 * g + 5) : 99;
      const int nw  = (jhi - jlo) + TB;            // 14 (13 for g=19)
      const int sb  = (t0 - jhi) & 127;            // wrap-free: offsets <= 13 slots
      const float* rp = &ring[sb * 64 + lane];

      float wv[14];
#pragma unroll
      for (int d = 0; d < nw; ++d) wv[d] = rp[d * 64];   // static ds offsets
      double X64[14];
#pragma unroll
      for (int d = 0; d < nw; ++d) X64[d] = (double)wv[d];
#pragma unroll
      for (int j = jlo; j <= jhi; ++j) {
        const double kk = kD[j];
#pragma unroll
        for (int i = 0; i < TB; ++i)
          acc[i] += kk * X64[i + (jhi - j)];       // x[t0 + i - j]
      }
      if (g & 1) __builtin_amdgcn_sched_barrier(0);  // cap hoisting, 2-deep pipe
    }

    // ---- phase 3: spike scan (exact f32 order, verified) ----
#pragma unroll
    for (int i = 0; i < TB; ++i) {
      float umem = (float)acc[i];
      float v  = __fsub_rn(__fadd_rn(umem, RX), THETA);
      bool  sp = (v >= 0.0f) && (h < HID);
      unsigned long long bal = __ballot(sp);
      if (lane == 0) mptr[(t0 + i) * 5] = bal;
      float sf = sp ? 1.0f : 0.0f;
      float y2 = __fadd_rn(RY, __fmul_rn(Af, sf));
      RX = __fmul_rn(arf, __fadd_rn(RX, y2));
      RY = __fmul_rn(arf, y2);
    }
    __builtin_amdgcn_sched_barrier(0);
  }
}

// ================== Kernel 2: layer-2 + head (per b) ======================
__global__ __launch_bounds__(320)
void snn_l2_kernel(const float* __restrict__ W2,
                   const unsigned long long* __restrict__ maskG,
                   float* __restrict__ out) {
  __shared__ double             kD[100];
  __shared__ double             W2D[2 * HID];
  __shared__ unsigned long long maskL[TLEN * 5];
  __shared__ double             zD[2 * 304];
  __shared__ float              u2L[2 * 304];
  __shared__ float              lgL[2];

  const int tid = threadIdx.x;
  const int b   = blockIdx.x;

  const float arf = (float)0.6065306597126334;
  const float Af  = (float)-27.182818284590452;

  for (int j = tid; j < 100; j += 320) {
    float q  = (float)j / 10.0f;
    float ef = (float)exp((double)(1.0f - q));
    kD[j] = (double)__fmul_rn(q, ef);
  }
  for (int i = tid; i < 2 * HID; i += 320)
    W2D[i] = (double)W2[i];
  for (int i = tid; i < TLEN * 5; i += 320)
    maskL[i] = maskG[(size_t)b * (TLEN * 5) + i];
  __syncthreads();

  // ---- fc2: flat ascending-h f64 chain, branchless (bit-identical) ----
  if (tid < TLEN) {
    const int t = tid;
    double z0 = 0.0, z1 = 0.0;
#pragma unroll
    for (int w5 = 0; w5 < 5; ++w5) {
      const unsigned long long mm = maskL[t * 5 + w5];
      const int kend = (w5 == 4) ? (HID - 256) : 64;
      for (int k = 0; k < kend; ++k) {
        const bool bit = (mm >> k) & 1ull;
        const int  hh  = w5 * 64 + k;
        z0 += bit ? W2D[hh] : 0.0;
        z1 += bit ? W2D[HID + hh] : 0.0;
      }
    }
    zD[t]       = (double)((float)z0);   // f32-rounded at tensor boundary
    zD[304 + t] = (double)((float)z1);
  }
  __syncthreads();

  // ---- psp2 (f64 accumulate, j ascending) ----
  if (tid < TLEN) {
    const int t = tid;
    double a0 = 0.0, a1 = 0.0;
    const int jmax = (t < KTAP) ? t : KTAP;
    for (int j = 1; j <= jmax; ++j) {
      const double kk = kD[j];
      a0 += kk * zD[t - j];
      a1 += kk * zD[304 + t - j];
    }
    u2L[t]       = (float)a0;
    u2L[304 + t] = (float)a1;
  }
  __syncthreads();

  // ---- layer-2 spike scan + count ----
  if (tid < 2) {
    float RX = 0.0f, RY = 0.0f;
    int cnt = 0;
    for (int t = 0; t < TLEN; ++t) {
      float u  = u2L[tid * 304 + t];
      float v  = __fsub_rn(__fadd_rn(u, RX), THETA);
      bool  sp = (v >= 0.0f);
      cnt += sp ? 1 : 0;
      float sf = sp ? 1.0f : 0.0f;
      float y2 = __fadd_rn(RY, __fmul_rn(Af, sf));
      RX = __fmul_rn(arf, __fadd_rn(RX, y2));
      RY = __fmul_rn(arf, y2);
    }
    lgL[tid] = (float)cnt;
  }
  __syncthreads();

  // ---- head (verified) ----
  if (tid == 0) {
    float l0 = lgL[0], l1 = lgL[1];
    uint32_t o0, o1;
    threefry2x32(0u, 2u * (uint32_t)b, o0, o1);
    float g0 = -logf(-logf(jax_uniform_from_bits(o0 ^ o1)));
    threefry2x32(0u, 2u * (uint32_t)b + 1u, o0, o1);
    float g1 = -logf(-logf(jax_uniform_from_bits(o0 ^ o1)));

    float v0 = __fadd_rn(l0, g0);
    float v1 = __fadd_rn(l1, g1);
    int   pi = (v1 > v0) ? 1 : 0;
    float m   = fmaxf(l0, l1);
    float s0f = __fsub_rn(l0, m), s1f = __fsub_rn(l1, m);
    float lse = logf(__fadd_rn(expf(s0f), expf(s1f)));
    float lp  = __fsub_rn(pi ? s1f : s0f, lse);

    out[2 * b + 0] = l0;
    out[2 * b + 1] = l1;
    out[2048 + b]  = (float)pi;
    out[3072 + b]  = lp;
  }
}

extern "C" void kernel_launch(void* const* d_in, const int* in_sizes, int n_in,
                              void* d_out, int out_size, void* d_ws, size_t ws_size,
                              hipStream_t stream) {
  const float* enc = (const float*)d_in[0];
  const float* W1  = (const float*)d_in[1];
  const float* W2  = (const float*)d_in[2];
  float* out = (float*)d_out;

  unsigned long long* maskG = (unsigned long long*)d_ws;  // 12.3 MB

  snn_l1_kernel<<<dim3(5, NB), dim3(64), 0, stream>>>(enc, W1, maskG);
  snn_l2_kernel<<<dim3(NB), dim3(320), 0, stream>>>(W2, maskG, out);
}